// Round 5
// baseline (27.896 us; speedup 1.0000x reference)
//
#include <hip/hip_runtime.h>
#include <hip/hip_bf16.h>
#include <math.h>

#define B_ 128
#define S_ 512
#define E_ 64
#define PAD_ 72  // bf16/row in LDS; 36-dword stride => 16B accesses 2-way (free)

typedef short bf16x8 __attribute__((ext_vector_type(8)));
typedef float f32x4 __attribute__((ext_vector_type(4)));

__device__ __forceinline__ unsigned short f2b(float f) {
  __hip_bfloat16 h = __float2bfloat16(f);
  unsigned short u;
  __builtin_memcpy(&u, &h, 2);
  return u;
}

// 512 blocks x 512 thr (8 waves), 2 blocks/CU. Block = (batch b, s-quarter sq):
// owns 128 s-rows, scans all 512 n. V (512 rows, fold w*cw) -> LDS bf16.
// U (128 rows) -> registers directly as MFMA A-fragments (lane layout of the
// phase-1 load IS the fragment layout). Wave (ws,wn) = 64 s x 128 n.
__global__ __launch_bounds__(512, 4) void fused_kernel(
    const float* __restrict__ ue, const float* __restrict__ ve,
    const float* __restrict__ cw, const float* __restrict__ mask,
    const float* __restrict__ pw, const float* __restrict__ pb,
    float* __restrict__ out) {
  __shared__ unsigned short vlds[S_ * PAD_];  // 73728 B
  __shared__ float comb[4][128];              // 2048 B

  // XCD swizzle: bx = (b%16)*32 + sq*8 + b/16  ->  all 4 sq-blocks of a batch
  // on one XCD (bx%8 = b/16), dispatched consecutively (L2-share the V panel).
  const int bx = blockIdx.x;
  const int b = (bx & 7) * 16 + (bx >> 5);
  const int sq = (bx >> 3) & 3;

  const int tid = threadIdx.x;
  const int wv = tid >> 6;  // 8 waves
  const int lane = tid & 63;
  const int c = lane & 15;  // MFMA col class / row-within-16
  const int g = lane >> 4;  // k-group
  const int ws = wv >> 2;   // s-split (0..1): 64 s-rows
  const int wn = wv & 3;    // n-split (0..3): 128 n

  const float w0 = pw[0];
  const float* __restrict__ vb = ve + (size_t)b * S_ * E_;
  const float* __restrict__ cwb = cw + (size_t)b * S_;
  const float* __restrict__ ub = ue + ((size_t)b * S_ + sq * 128) * E_;
  const float* __restrict__ mb = mask + (size_t)b * S_;

  // ---- Issue U loads early: rows ws*64 + st*16 + c, k in [8g,8g+8)+[32+8g,+8)
  f32x4 xu[4][4];
#pragma unroll
  for (int st = 0; st < 4; ++st) {
    const float* r = ub + (size_t)(ws * 64 + st * 16 + c) * E_;
    xu[st][0] = *(const f32x4*)(r + 8 * g);
    xu[st][1] = *(const f32x4*)(r + 8 * g + 4);
    xu[st][2] = *(const f32x4*)(r + 8 * g + 32);
    xu[st][3] = *(const f32x4*)(r + 8 * g + 36);
  }
  float pen[8];  // mask penalty for this wave's 8 n-tiles, column c
#pragma unroll
  for (int j = 0; j < 8; ++j)
    pen[j] = (mb[(wn * 8 + j) * 16 + c] > 0.5f) ? 0.0f : -1e30f;

  // ---- V: wave owns 64 rows; lane (c,g) row base+q*16+c cols [16g,16g+16) ----
#pragma unroll
  for (int q = 0; q < 4; ++q) {
    const int row = wv * 64 + q * 16 + c;
    const float* r = vb + (size_t)row * E_ + g * 16;
    f32x4 x0 = *(const f32x4*)(r);
    f32x4 x1 = *(const f32x4*)(r + 4);
    f32x4 x2 = *(const f32x4*)(r + 8);
    f32x4 x3 = *(const f32x4*)(r + 12);
    float ss = 0.f;
#pragma unroll
    for (int j = 0; j < 4; ++j)
      ss = fmaf(x0[j], x0[j], fmaf(x1[j], x1[j], fmaf(x2[j], x2[j], fmaf(x3[j], x3[j], ss))));
    ss += __shfl_xor(ss, 16);
    ss += __shfl_xor(ss, 32);
    float s = (w0 * cwb[row]) / fmaxf(sqrtf(ss), 1e-7f);
    bf16x8 o0, o1;
#pragma unroll
    for (int j = 0; j < 4; ++j) {
      o0[j] = (short)f2b(x0[j] * s); o0[4 + j] = (short)f2b(x1[j] * s);
      o1[j] = (short)f2b(x2[j] * s); o1[4 + j] = (short)f2b(x3[j] * s);
    }
    unsigned short* dst = vlds + (size_t)row * PAD_ + g * 16;
    *(bf16x8*)dst = o0;
    *(bf16x8*)(dst + 8) = o1;
  }

  // ---- U: normalize in-register -> A-fragments a[st][0..1] ----
  bf16x8 a[4][2];
#pragma unroll
  for (int st = 0; st < 4; ++st) {
    float ss = 0.f;
#pragma unroll
    for (int i = 0; i < 4; ++i)
#pragma unroll
      for (int j = 0; j < 4; ++j) ss = fmaf(xu[st][i][j], xu[st][i][j], ss);
    ss += __shfl_xor(ss, 16);
    ss += __shfl_xor(ss, 32);
    float s = 1.0f / fmaxf(sqrtf(ss), 1e-7f);
#pragma unroll
    for (int j = 0; j < 4; ++j) {
      a[st][0][j] = (short)f2b(xu[st][0][j] * s);
      a[st][0][4 + j] = (short)f2b(xu[st][1][j] * s);
      a[st][1][j] = (short)f2b(xu[st][2][j] * s);
      a[st][1][4 + j] = (short)f2b(xu[st][3][j] * s);
    }
  }

  __syncthreads();

  // ---- Phase 2: MFMA max-scan; mask folded into C-operand ----
  float r[4][4];
#pragma unroll
  for (int st = 0; st < 4; ++st)
#pragma unroll
    for (int i = 0; i < 4; ++i) r[st][i] = -INFINITY;

#pragma unroll
  for (int j = 0; j < 8; ++j) {
    const int it = wn * 8 + j;
    const unsigned short* vr = vlds + (size_t)(it * 16 + c) * PAD_ + g * 8;
    bf16x8 b0 = *(const bf16x8*)(vr);
    bf16x8 b1 = *(const bf16x8*)(vr + 32);
    f32x4 ci = {pen[j], pen[j], pen[j], pen[j]};
#pragma unroll
    for (int st = 0; st < 4; ++st) {
      f32x4 acc = __builtin_amdgcn_mfma_f32_16x16x32_bf16(a[st][0], b0, ci, 0, 0, 0);
      acc = __builtin_amdgcn_mfma_f32_16x16x32_bf16(a[st][1], b1, acc, 0, 0, 0);
      r[st][0] = fmaxf(r[st][0], acc[0]);
      r[st][1] = fmaxf(r[st][1], acc[1]);
      r[st][2] = fmaxf(r[st][2], acc[2]);
      r[st][3] = fmaxf(r[st][3], acc[3]);
    }
  }

  // ---- Reduce over 16 column-lanes (xor 1,2,4,8: stays within kg group) ----
#pragma unroll
  for (int st = 0; st < 4; ++st)
#pragma unroll
    for (int i = 0; i < 4; ++i) {
      float v = r[st][i];
      v = fmaxf(v, __shfl_xor(v, 1)); v = fmaxf(v, __shfl_xor(v, 2));
      v = fmaxf(v, __shfl_xor(v, 4)); v = fmaxf(v, __shfl_xor(v, 8));
      r[st][i] = v;
    }

  if (c == 0) {
#pragma unroll
    for (int st = 0; st < 4; ++st)
#pragma unroll
      for (int i = 0; i < 4; ++i)
        comb[wn][ws * 64 + st * 16 + g * 4 + i] = r[st][i];
  }

  __syncthreads();

  // ---- Final: combine n-splits + sigmoid, 128 outputs ----
  if (tid < 128) {
    float v = fmaxf(fmaxf(comb[0][tid], comb[1][tid]),
                    fmaxf(comb[2][tid], comb[3][tid]));
    float bias = pb[0];
    out[(size_t)b * S_ + sq * 128 + tid] =
        (v < -1e29f) ? 0.0f : 1.0f / (1.0f + expf(-(v + bias)));
  }
}

extern "C" void kernel_launch(void* const* d_in, const int* in_sizes, int n_in,
                              void* d_out, int out_size, void* d_ws, size_t ws_size,
                              hipStream_t stream) {
  const float* ue = (const float*)d_in[0];
  const float* ve = (const float*)d_in[1];
  const float* cw = (const float*)d_in[2];
  const float* mask = (const float*)d_in[3];
  const float* pw = (const float*)d_in[4];
  const float* pb = (const float*)d_in[5];
  float* out = (float*)d_out;

  hipLaunchKernelGGL(fused_kernel, dim3(4 * B_), dim3(512), 0, stream,
                     ue, ve, cw, mask, pw, pb, out);
}